// Round 4
// baseline (982.707 us; speedup 1.0000x reference)
//
#include <hip/hip_runtime.h>
#include <hip/hip_fp16.h>

#define NNODES   100000
#define NFEAT    16
#define NEDGES   3200000
#define NLAYERS  4
#define NBUCKETS 3125        // 100000 / 32 exactly
#define BCAP     736         // per-half bucket capacity (mean 512, +9.9 sigma)
#define EHALF    1600000

// ---------------- node histogram ----------------
__global__ __launch_bounds__(256) void hist_kernel(
    const int* __restrict__ dst, int* __restrict__ deg)
{
    int e = blockIdx.x * 256 + threadIdx.x;
    if (e < NEDGES) atomicAdd(&deg[dst[e]], 1);
}

// ---------------- scan deg -> offs ----------------
#define SCAN_T 1024
#define SCAN_CHUNK 98
__global__ __launch_bounds__(SCAN_T) void scan_kernel(
    const int* __restrict__ deg, int* __restrict__ offs)
{
    __shared__ int part[SCAN_T];
    int t = threadIdx.x;
    int base = t * SCAN_CHUNK;
    int s = 0;
    for (int i = 0; i < SCAN_CHUNK; ++i) {
        int idx = base + i;
        if (idx < NNODES) s += deg[idx];
    }
    part[t] = s;
    __syncthreads();
    for (int off = 1; off < SCAN_T; off <<= 1) {
        int v = (t >= off) ? part[t - off] : 0;
        __syncthreads();
        part[t] += v;
        __syncthreads();
    }
    int run = (t == 0) ? 0 : part[t - 1];
    for (int i = 0; i < SCAN_CHUNK; ++i) {
        int idx = base + i;
        if (idx < NNODES) { offs[idx] = run; run += deg[idx]; }
    }
    if (t == SCAN_T - 1) offs[NNODES] = run;
}

// ---------------- Phase A: bin edges by dst bucket ----------------
// entry: 3 dwords {src | dlocal<<17, half2(w0,w1), half2(w2,w3)}
__global__ __launch_bounds__(256) void binA_kernel(
    const int*   __restrict__ src,
    const int*   __restrict__ dst,
    const float* __restrict__ wt,
    const float* __restrict__ lw,
    int ebase, int ecount,
    int*          __restrict__ bcur,
    unsigned int* __restrict__ bins)
{
    int i = blockIdx.x * 256 + threadIdx.x;
    if (i >= ecount) return;
    int e = ebase + i;
    int d = dst[e];
    int b = d >> 5;
    float w = wt[e];
    __half2 w01 = __floats2half2_rn(w * lw[0 * NEDGES + e], w * lw[1 * NEDGES + e]);
    __half2 w23 = __floats2half2_rn(w * lw[2 * NEDGES + e], w * lw[3 * NEDGES + e]);
    int rel = atomicAdd(&bcur[b], 1);
    if (rel >= BCAP) return;   // statistically impossible; guards corruption
    unsigned int a = (unsigned int)src[e] | ((unsigned int)(d & 31) << 17);
    unsigned int* p = bins + 3u * (unsigned int)(b * BCAP + rel);
    p[0] = a;
    p[1] = *(const unsigned int*)&w01;
    p[2] = *(const unsigned int*)&w23;
}

// ---------------- Phase B: bins -> exact CSR (SoA, f16 weights) ----------------
__global__ __launch_bounds__(256) void binB_kernel(
    const int*          __restrict__ bcur,
    const unsigned int* __restrict__ bins,
    int*                __restrict__ ncur,
    unsigned int*       __restrict__ csr_src,
    __half*             __restrict__ w0,
    __half*             __restrict__ w1,
    __half*             __restrict__ w2,
    __half*             __restrict__ w3)
{
    int b = blockIdx.x;
    int cnt = bcur[b];
    if (cnt > BCAP) cnt = BCAP;
    const unsigned int* base = bins + 3u * (unsigned int)(b * BCAP);
    for (int i = threadIdx.x; i < cnt; i += 256) {
        unsigned int a   = base[3 * i + 0];
        unsigned int u01 = base[3 * i + 1];
        unsigned int u23 = base[3 * i + 2];
        int s = (int)(a & 0x1FFFF);
        int d = (b << 5) | (int)((a >> 17) & 31);
        int slot = atomicAdd(&ncur[d], 1);
        __half2 h01 = *(const __half2*)&u01;
        __half2 h23 = *(const __half2*)&u23;
        csr_src[slot] = (unsigned int)s;
        w0[slot] = __low2half(h01);
        w1[slot] = __high2half(h01);
        w2[slot] = __low2half(h23);
        w3[slot] = __high2half(h23);
    }
}

// ---------------- pull: 8 lanes/node, half2 features ----------------
// MODE 0: f32 input, out = f16(acc + h0)
// MODE 1: f16 input, out = f16(acc + h0)
// MODE 2: f16 input, out = f32 sigmoid(2*acc)
template<int MODE>
__global__ __launch_bounds__(256) void pull8_kernel(
    const int*          __restrict__ offs,
    const unsigned int* __restrict__ csr_src,
    const __half*       __restrict__ wk,
    const void*         __restrict__ hin,
    const float*        __restrict__ h0,
    void*               __restrict__ hout)
{
    int t = blockIdx.x * 256 + threadIdx.x;
    int g = t >> 3;
    if (g >= NNODES) return;
    int l = t & 7;
    int j = offs[g], j1 = offs[g + 1];

    const __half2* h16 = (const __half2*)hin;
    const float2*  h32 = (const float2*)hin;

    float ax = 0.f, ay = 0.f;
    for (; j + 1 < j1; j += 2) {
        unsigned int s0 = csr_src[j], s1 = csr_src[j + 1];
        float wa = __half2float(wk[j]);
        float wb = __half2float(wk[j + 1]);
        float hx0, hy0, hx1, hy1;
        if (MODE == 0) {
            float2 v0 = h32[(size_t)s0 * 8 + l];
            float2 v1 = h32[(size_t)s1 * 8 + l];
            hx0 = v0.x; hy0 = v0.y; hx1 = v1.x; hy1 = v1.y;
        } else {
            float2 v0 = __half22float2(h16[(size_t)s0 * 8 + l]);
            float2 v1 = __half22float2(h16[(size_t)s1 * 8 + l]);
            hx0 = v0.x; hy0 = v0.y; hx1 = v1.x; hy1 = v1.y;
        }
        ax = fmaf(wa, hx0, ax); ay = fmaf(wa, hy0, ay);
        ax = fmaf(wb, hx1, ax); ay = fmaf(wb, hy1, ay);
    }
    if (j < j1) {
        unsigned int s0 = csr_src[j];
        float wa = __half2float(wk[j]);
        float hx0, hy0;
        if (MODE == 0) {
            float2 v0 = h32[(size_t)s0 * 8 + l];
            hx0 = v0.x; hy0 = v0.y;
        } else {
            float2 v0 = __half22float2(h16[(size_t)s0 * 8 + l]);
            hx0 = v0.x; hy0 = v0.y;
        }
        ax = fmaf(wa, hx0, ax); ay = fmaf(wa, hy0, ay);
    }

    int o = g * 8 + l;
    if (MODE == 2) {
        float2 r;
        r.x = 1.f / (1.f + expf(-2.f * ax));
        r.y = 1.f / (1.f + expf(-2.f * ay));
        ((float2*)hout)[o] = r;
    } else {
        float2 r0 = ((const float2*)h0)[o];
        ((__half2*)hout)[o] = __floats2half2_rn(ax + r0.x, ay + r0.y);
    }
}

// ---------------- fallback (atomic push path) ----------------
__global__ __launch_bounds__(256) void scatter_layer(
    const int* __restrict__ src, const int* __restrict__ dst,
    const float* __restrict__ wt, const float* __restrict__ lw,
    const float* __restrict__ h, float* __restrict__ acc)
{
    long t = (long)blockIdx.x * blockDim.x + threadIdx.x;
    int e = (int)(t >> 4);
    if (e >= NEDGES) return;
    int f = (int)(t & 15);
    float w = wt[e] * lw[e];
    atomicAdd(&acc[dst[e] * NFEAT + f], w * h[src[e] * NFEAT + f]);
}
__global__ __launch_bounds__(256) void sigmoid_inplace(float* __restrict__ out, int n)
{
    int i = blockIdx.x * blockDim.x + threadIdx.x;
    if (i < n) out[i] = 1.f / (1.f + expf(-2.f * out[i]));
}

// ---------------- launch ----------------
extern "C" void kernel_launch(void* const* d_in, const int* in_sizes, int n_in,
                              void* d_out, int out_size, void* d_ws, size_t ws_size,
                              hipStream_t stream)
{
    const float* h0 = (const float*)d_in[0];
    const int*   ei = (const int*)d_in[1];     // int32 (JAX x64 off)
    const float* wt = (const float*)d_in[2];
    const float* lw = (const float*)d_in[3];

    const int* src = ei;
    const int* dst = ei + NEDGES;

    const size_t hbytes = (size_t)NNODES * NFEAT * sizeof(float);

    // workspace layout (bytes)
    const size_t off_deg  = 0;                                  // int[100000]
    const size_t off_offs = 400128;                             // int[100001]
    const size_t off_bcur = 800384;                             // int[3125]
    const size_t off_csr  = 812928;                             // u32[NEDGES]       12.8 MB
    const size_t off_w    = off_csr + (size_t)NEDGES * 4;       // f16[4][NEDGES]    25.6 MB
    const size_t off_bins = off_w + (size_t)4 * NEDGES * 2;     // u32[3*3125*736]   27.6 MB
    const size_t need     = off_bins + (size_t)3 * NBUCKETS * BCAP * 4;

    if (ws_size < need) {
        // fallback: atomic push path (round-1, needs only 6.4 MB)
        float* hw = (float*)d_ws;
        float* ho = (float*)d_out;
        dim3 blk(256), grd(((long)NEDGES * 16 + 255) / 256);
        hipMemcpyAsync(hw, h0, hbytes, hipMemcpyDeviceToDevice, stream);
        scatter_layer<<<grd, blk, 0, stream>>>(src, dst, wt, lw + 0L * NEDGES, h0, hw);
        hipMemcpyAsync(ho, h0, hbytes, hipMemcpyDeviceToDevice, stream);
        scatter_layer<<<grd, blk, 0, stream>>>(src, dst, wt, lw + 1L * NEDGES, hw, ho);
        hipMemcpyAsync(hw, h0, hbytes, hipMemcpyDeviceToDevice, stream);
        scatter_layer<<<grd, blk, 0, stream>>>(src, dst, wt, lw + 2L * NEDGES, ho, hw);
        hipMemsetAsync(ho, 0, hbytes, stream);
        scatter_layer<<<grd, blk, 0, stream>>>(src, dst, wt, lw + 3L * NEDGES, hw, ho);
        int n = NNODES * NFEAT;
        sigmoid_inplace<<<(n + 255) / 256, 256, 0, stream>>>(ho, n);
        return;
    }

    char* ws = (char*)d_ws;
    int*          deg     = (int*)(ws + off_deg);    // reused as node cursor
    int*          offs    = (int*)(ws + off_offs);
    int*          bcur    = (int*)(ws + off_bcur);
    unsigned int* csr_src = (unsigned int*)(ws + off_csr);
    __half*       w0      = (__half*)(ws + off_w);
    __half*       w1      = w0 + NEDGES;
    __half*       w2      = w1 + NEDGES;
    __half*       w3      = w2 + NEDGES;
    unsigned int* bins    = (unsigned int*)(ws + off_bins);
    __half*       hbA     = (__half*)(ws + off_bins);   // aliases bins (dead after build)
    __half*       hbB     = (__half*)d_out;             // lower half of d_out as f16 scratch
    float*        hout    = (float*)d_out;

    // ---- node histogram + scan ----
    hipMemsetAsync(deg, 0, (size_t)NNODES * 4, stream);
    hist_kernel<<<(NEDGES + 255) / 256, 256, 0, stream>>>(dst, deg);
    scan_kernel<<<1, SCAN_T, 0, stream>>>(deg, offs);
    hipMemcpyAsync(deg, offs, (size_t)NNODES * 4, hipMemcpyDeviceToDevice, stream); // node cursors

    // ---- two-half binned CSR build ----
    dim3 blkA(256), grdA((EHALF + 255) / 256);
    // half 0
    hipMemsetAsync(bcur, 0, (size_t)NBUCKETS * 4, stream);
    binA_kernel<<<grdA, blkA, 0, stream>>>(src, dst, wt, lw, 0, EHALF, bcur, bins);
    binB_kernel<<<NBUCKETS, 256, 0, stream>>>(bcur, bins, deg, csr_src, w0, w1, w2, w3);
    // half 1
    hipMemsetAsync(bcur, 0, (size_t)NBUCKETS * 4, stream);
    binA_kernel<<<grdA, blkA, 0, stream>>>(src, dst, wt, lw, EHALF, NEDGES - EHALF, bcur, bins);
    binB_kernel<<<NBUCKETS, 256, 0, stream>>>(bcur, bins, deg, csr_src, w0, w1, w2, w3);

    // ---- 4 pull layers (8 lanes/node, half2) ----
    dim3 blk(256), grd((NNODES * 8 + 255) / 256);
    pull8_kernel<0><<<grd, blk, 0, stream>>>(offs, csr_src, w0, h0,  h0, hbA);
    pull8_kernel<1><<<grd, blk, 0, stream>>>(offs, csr_src, w1, hbA, h0, hbB);
    pull8_kernel<1><<<grd, blk, 0, stream>>>(offs, csr_src, w2, hbB, h0, hbA);
    pull8_kernel<2><<<grd, blk, 0, stream>>>(offs, csr_src, w3, hbA, h0, hout);
}